// Round 9
// baseline (164.330 us; speedup 1.0000x reference)
//
#include <hip/hip_runtime.h>
#include <cstdint>
#include <cstddef>

#define Bn 8192
#define Dn 1024
#define Hn 1024
#define En 8
#define MT 128                     // expert padding quantum / m-tile
#define MTILES (PERM_N / MT)       // 72
#define PERM_N (Bn + En * MT)      // 9216
#define NB 16                      // 64-col partial chunks per row

// prep_k block ranges
#define NXB 4096                   // x-convert blocks
#define NWB 2048                   // W1-transpose blocks
#define XB0 1
#define WB0 (XB0 + NXB)
#define TOTB (WB0 + NWB)           // 6145

typedef unsigned short u16;
typedef __bf16 bf16x8 __attribute__((ext_vector_type(8)));
typedef float f32x4 __attribute__((ext_vector_type(4)));
typedef unsigned short ushort8 __attribute__((ext_vector_type(8)));

// ---------- helpers ----------
__device__ __forceinline__ u16 f2bf(float f) {
  unsigned int u = __float_as_uint(f);
  unsigned int r = u + 0x7fffu + ((u >> 16) & 1u);   // RNE
  return (u16)(r >> 16);
}

__device__ __forceinline__ void gld16(const void* g, void* l) {
  __builtin_amdgcn_global_load_lds(
      (const __attribute__((address_space(1))) void*)g,
      (__attribute__((address_space(3))) void*)l, 16, 0, 0);
}

// wait for own vmcnt<=N (lgkm/exp untouched), then workgroup barrier.
// imm: vmcnt[3:0] | expcnt[6:4] | lgkmcnt[11:8]
#define PIPE_BARRIER_VM3() do {                    \
    asm volatile("" ::: "memory");                 \
    __builtin_amdgcn_s_waitcnt(0x0F73);            \
    __builtin_amdgcn_s_barrier();                  \
    asm volatile("" ::: "memory");                 \
  } while (0)
#define PIPE_BARRIER_VM0() do {                    \
    asm volatile("" ::: "memory");                 \
    __builtin_amdgcn_s_waitcnt(0x0F70);            \
    __builtin_amdgcn_s_barrier();                  \
    asm volatile("" ::: "memory");                 \
  } while (0)

// ---------- D1: routing (block 0) + x->bf16 natural (1..4096) + W1^T (4097..6144) ----
__global__ __launch_bounds__(256) void prep_k(
    const float* __restrict__ x, const int* __restrict__ sidx,
    const float* __restrict__ W1,
    u16* __restrict__ xb, u16* __restrict__ w1t,
    int* __restrict__ off, int* __restrict__ perm) {
  int bid = blockIdx.x;
  int t = threadIdx.x;

  if (bid == 0) {
    // ---- routing (single block, 256 threads, 4 waves) ----
    __shared__ int hist[4][En];
    __shared__ int base[4][En];
    __shared__ int eoff[En + 1];
    int wv = t >> 6;
    if (t < 4 * En) ((int*)hist)[t] = 0;
#pragma unroll
    for (int i = 0; i < PERM_N / 256; i++) perm[t + i * 256] = -1;  // pad fill
    __syncthreads();
    int e32[32], r32[32];
#pragma unroll
    for (int i = 0; i < 32; i++) {
      int e = sidx[t + i * 256];
      e32[i] = e;
      r32[i] = atomicAdd(&hist[wv][e], 1);
    }
    __syncthreads();
    if (t < En) {
      int s = 0;
      for (int w = 0; w < 4; w++) { base[w][t] = s; s += hist[w][t]; }
      hist[0][t] = s;
    }
    __syncthreads();
    if (t == 0) {
      int o = 0;
      for (int e = 0; e < En; e++) {
        eoff[e] = o; off[e] = o;
        o += (hist[0][e] + MT - 1) & ~(MT - 1);
      }
      eoff[En] = o; off[En] = o;
    }
    __syncthreads();
#pragma unroll
    for (int i = 0; i < 32; i++) {
      int e = e32[i];
      perm[eoff[e] + base[wv][e] + r32[i]] = t + i * 256;
    }
  } else if (bid < WB0) {
    // ---- x fp32 -> bf16, natural order (no perm dependency) ----
    size_t idx = ((size_t)(bid - XB0) * 256 + t) * 8;
    const float* src = x + idx;
    float4 a = *(const float4*)src;
    float4 b = *(const float4*)(src + 4);
    ushort8 o;
    o[0] = f2bf(a.x); o[1] = f2bf(a.y); o[2] = f2bf(a.z); o[3] = f2bf(a.w);
    o[4] = f2bf(b.x); o[5] = f2bf(b.y); o[6] = f2bf(b.z); o[7] = f2bf(b.w);
    *(ushort8*)(xb + idx) = o;
  } else {
    // ---- W1 [E][D][H] fp32 -> W1t [E][H][D] bf16, 64x64 LDS transpose ----
    __shared__ float tile[64][65];
    int wb = bid - WB0;
    int e = wb >> 8;
    int k0 = ((wb >> 4) & 15) * 64;   // D
    int n0 = (wb & 15) * 64;          // H
    int c4 = (t & 15) * 4;
    int r0 = t >> 4;                  // 0..15
    const float* src = W1 + ((size_t)e << 20) + (size_t)k0 * Hn + n0;
#pragma unroll
    for (int i = 0; i < 4; i++) {
      int r = r0 + i * 16;
      float4 v = *(const float4*)(src + (size_t)r * Hn + c4);
      tile[r][c4 + 0] = v.x; tile[r][c4 + 1] = v.y;
      tile[r][c4 + 2] = v.z; tile[r][c4 + 3] = v.w;
    }
    __syncthreads();
    u16* dst = w1t + ((size_t)e << 20) + (size_t)n0 * Dn + k0;
#pragma unroll
    for (int i = 0; i < 4; i++) {
      int h = r0 + i * 16;
      ushort4 o;
      o.x = f2bf(tile[c4 + 0][h]);
      o.y = f2bf(tile[c4 + 1][h]);
      o.z = f2bf(tile[c4 + 2][h]);
      o.w = f2bf(tile[c4 + 3][h]);
      *(ushort4*)(dst + (size_t)h * Dn + c4) = o;
    }
  }
}

// ---------- D2: grouped GEMM, 128x64 tile, 3-stage vmcnt(3) pipeline,
// ---------- 36 KB LDS -> 4 blocks/CU, in-staging A-gather, partials epilogue ----------
__global__ __launch_bounds__(256) void gemm_k(
    const u16* __restrict__ xb, const u16* __restrict__ w1t,
    const float* __restrict__ b1, const float* __restrict__ w2,
    const int* __restrict__ off, const int* __restrict__ perm,
    float* __restrict__ partials) {
  __shared__ u16 As[3][4096];   // 3 stages x 128 rows x 32 k (8 KB each)
  __shared__ u16 Bs[3][2048];   // 3 stages x  64 rows x 32 k (4 KB each)

  int n0 = blockIdx.x * 64;             // x = n-slice: 16 slices, 2 per XCD
  int row0 = blockIdx.y * MT;
  if (row0 >= off[En]) return;          // dead (all-pad) tile
  int e = 0;
  while (row0 >= off[e + 1]) e++;

  int tid = threadIdx.x;
  int lane = tid & 63, w = tid >> 6;    // 4 waves; wave w owns rows 32w..32w+31

  // staging: HW puts lane L at LDS base + L*16B -> (row L>>2, slot L&3).
  // source chunk q = slot ^ swz(row) implements the xor swizzle.
  int srow = lane >> 2;
  int slot = lane & 3;
  int scol = (slot ^ ((srow >> 1) & 3)) * 8;
  const u16* aG[2];
  int lOffA[2];
#pragma unroll
  for (int j = 0; j < 2; j++) {
    int rl = 32 * w + 16 * j + srow;
    int tok = perm[row0 + rl];
    if (tok < 0) tok = 0;               // pad row: any valid row (result discarded)
    aG[j] = xb + ((size_t)tok << 10) + scol;
    lOffA[j] = (32 * w + 16 * j) * 32;  // wave-uniform LDS base (elements)
  }
  // B: wave w stages rows 16w..16w+15 of the 64-row slice
  const u16* bG = w1t + ((size_t)e << 20) + (size_t)(n0 + 16 * w + srow) * Dn + scol;
  int lOffB = (16 * w) * 32;

  f32x4 acc[2][4];
#pragma unroll
  for (int i = 0; i < 2; i++)
#pragma unroll
    for (int j = 0; j < 4; j++)
      acc[i][j] = (f32x4){0.f, 0.f, 0.f, 0.f};

  int fr = lane & 15;
  int qf = lane >> 4;
  int qs = (qf ^ ((fr >> 1) & 3)) * 8;
  int offA[2], offB[4];
#pragma unroll
  for (int i = 0; i < 2; i++)
    offA[i] = (w * 32 + i * 16 + fr) * 32 + qs;
#pragma unroll
  for (int j = 0; j < 4; j++)
    offB[j] = (j * 16 + fr) * 32 + qs;

  // prologue: stages 0,1 in flight (3 loads/thread each)
#pragma unroll
  for (int it = 0; it < 2; it++) {
    int ko = it * 32;
    gld16(aG[0] + ko, (u16*)As[it] + lOffA[0]);
    gld16(aG[1] + ko, (u16*)As[it] + lOffA[1]);
    gld16(bG + ko, (u16*)Bs[it] + lOffB);
  }

#pragma unroll
  for (int i = 0; i < 31; i++) {
    PIPE_BARRIER_VM3();                 // stage-i loads done; stage-(i+1) in flight
    if (i + 2 < 32) {
      int s = (i + 2) % 3;
      int ko = (i + 2) * 32;
      gld16(aG[0] + ko, (u16*)As[s] + lOffA[0]);
      gld16(aG[1] + ko, (u16*)As[s] + lOffA[1]);
      gld16(bG + ko, (u16*)Bs[s] + lOffB);
    }
    const u16* Ab = (const u16*)As[i % 3];
    const u16* Bb = (const u16*)Bs[i % 3];
    bf16x8 af[2], bfr[4];
#pragma unroll
    for (int ii = 0; ii < 2; ii++) af[ii] = *(const bf16x8*)(Ab + offA[ii]);
#pragma unroll
    for (int jj = 0; jj < 4; jj++) bfr[jj] = *(const bf16x8*)(Bb + offB[jj]);
#pragma unroll
    for (int ii = 0; ii < 2; ii++)
#pragma unroll
      for (int jj = 0; jj < 4; jj++)
        acc[ii][jj] = __builtin_amdgcn_mfma_f32_16x16x32_bf16(af[ii], bfr[jj], acc[ii][jj], 0, 0, 0);
  }
  {                                     // peeled last iteration (full drain)
    PIPE_BARRIER_VM0();
    const u16* Ab = (const u16*)As[31 % 3];
    const u16* Bb = (const u16*)Bs[31 % 3];
    bf16x8 af[2], bfr[4];
#pragma unroll
    for (int ii = 0; ii < 2; ii++) af[ii] = *(const bf16x8*)(Ab + offA[ii]);
#pragma unroll
    for (int jj = 0; jj < 4; jj++) bfr[jj] = *(const bf16x8*)(Bb + offB[jj]);
#pragma unroll
    for (int ii = 0; ii < 2; ii++)
#pragma unroll
      for (int jj = 0; jj < 4; jj++)
        acc[ii][jj] = __builtin_amdgcn_mfma_f32_16x16x32_bf16(af[ii], bfr[jj], acc[ii][jj], 0, 0, 0);
  }

  // epilogue: h = relu(acc + b1); partial = h . W2[e][col][0..3]; float4 per row/chunk
  float4 w2v[4]; float b1v[4];
#pragma unroll
  for (int j = 0; j < 4; j++) {
    int col = n0 + j * 16 + fr;
    w2v[j] = *(const float4*)(w2 + ((size_t)e * Hn + col) * 4);
    b1v[j] = b1[(size_t)e * Hn + col];
  }
  int chunk = blockIdx.x;               // 64-col chunk 0..15
#pragma unroll
  for (int i = 0; i < 2; i++) {
    int rbase = w * 32 + i * 16 + qf * 4;
#pragma unroll
    for (int r = 0; r < 4; r++) {
      float s0 = 0.f, s1 = 0.f, s2 = 0.f, s3 = 0.f;
#pragma unroll
      for (int j = 0; j < 4; j++) {
        float h = acc[i][j][r] + b1v[j];
        h = fmaxf(h, 0.f);
        s0 = fmaf(h, w2v[j].x, s0);
        s1 = fmaf(h, w2v[j].y, s1);
        s2 = fmaf(h, w2v[j].z, s2);
        s3 = fmaf(h, w2v[j].w, s3);
      }
#pragma unroll
      for (int m = 1; m < 16; m <<= 1) {
        s0 += __shfl_xor(s0, m);
        s1 += __shfl_xor(s1, m);
        s2 += __shfl_xor(s2, m);
        s3 += __shfl_xor(s3, m);
      }
      if (fr == 0) {
        int row = row0 + rbase + r;
        *(float4*)(partials + ((size_t)row * NB + chunk) * 4) =
            make_float4(s0, s1, s2, s3);
      }
    }
  }
}

// ---------- D3: reduce partials + ordinal probs ----------
__global__ void probs_k(const float* __restrict__ partials,
                        const int* __restrict__ perm, const int* __restrict__ off,
                        const int* __restrict__ sidx, const float* __restrict__ b2,
                        float* __restrict__ out) {
  int p = blockIdx.x * blockDim.x + threadIdx.x;
  if (p >= off[En]) return;
  int tok = perm[p];
  if (tok < 0) return;
  int e = sidx[tok];
  float s0 = 0.f, s1 = 0.f, s2 = 0.f, s3 = 0.f;
#pragma unroll
  for (int nb = 0; nb < NB; nb++) {
    float4 v = *(const float4*)(partials + ((size_t)p * NB + nb) * 4);
    s0 += v.x; s1 += v.y; s2 += v.z; s3 += v.w;
  }
  float l0 = s0 + b2[e * 4 + 0];
  float l1 = s1 + b2[e * 4 + 1];
  float l2 = s2 + b2[e * 4 + 2];
  float l3 = s3 + b2[e * 4 + 3];
  out[tok * 4 + 0] = l0; out[tok * 4 + 1] = l1;
  out[tok * 4 + 2] = l2; out[tok * 4 + 3] = l3;
  float q0 = 1.f / (1.f + expf(-l0));
  float q1 = 1.f / (1.f + expf(-l1));
  float q2 = 1.f / (1.f + expf(-l2));
  float q3 = 1.f / (1.f + expf(-l3));
  const float eps = 1e-8f;
  float p0 = fmaxf(1.f - q0, eps);
  float p1 = fmaxf(q0 - q1, eps);
  float p2 = fmaxf(q1 - q2, eps);
  float p3 = fmaxf(q2 - q3, eps);
  float p4 = fmaxf(q3, eps);
  float s = p0 + p1 + p2 + p3 + p4;
  float inv = 1.f / fmaxf(s, eps);
  float* pr = out + (size_t)Bn * 4 + (size_t)tok * 5;
  pr[0] = p0 * inv; pr[1] = p1 * inv; pr[2] = p2 * inv;
  pr[3] = p3 * inv; pr[4] = p4 * inv;
}

// ---------- launch ----------
extern "C" void kernel_launch(void* const* d_in, const int* in_sizes, int n_in,
                              void* d_out, int out_size, void* d_ws, size_t ws_size,
                              hipStream_t stream) {
  const float* x  = (const float*)d_in[0];
  const int* sidx = (const int*)d_in[1];
  const float* W1 = (const float*)d_in[2];
  const float* b1 = (const float*)d_in[3];
  const float* W2 = (const float*)d_in[4];
  const float* b2 = (const float*)d_in[5];
  float* out = (float*)d_out;

  uint8_t* w = (uint8_t*)d_ws;
  int* off  = (int*)(w + 64);     // 9 ints
  int* perm = (int*)(w + 512);    // 9216 ints
  u16* xb      = (u16*)(w + 40960);                    // 16,777,216 B
  u16* w1t     = (u16*)(w + 40960 + 16777216);         // 16,777,216 B
  float* parts = (float*)(w + 40960 + 2 * 16777216);   // 2,359,296 B

  prep_k<<<TOTB, 256, 0, stream>>>(x, sidx, W1, xb, w1t, off, perm);
  gemm_k<<<dim3(16, MTILES), 256, 0, stream>>>(xb, w1t, b1, W2, off, perm, parts);
  probs_k<<<(PERM_N + 255) / 256, 256, 0, stream>>>(parts, perm, off, sidx, b2, out);
}

// Round 10
// 156.982 us; speedup vs baseline: 1.0468x; 1.0468x over previous
//
#include <hip/hip_runtime.h>
#include <cstdint>
#include <cstddef>

#define Bn 8192
#define Dn 1024
#define Hn 1024
#define En 8
#define MT 128                     // expert padding quantum / m-tile
#define MTILES (PERM_N / MT)       // 72
#define PERM_N (Bn + En * MT)      // 9216
#define NB 16                      // 64-col partial chunks per row

// prep_k block ranges
#define NXB 4096                   // x-convert blocks
#define NWB 2048                   // W1-transpose blocks
#define XB0 1
#define WB0 (XB0 + NXB)
#define TOTB (WB0 + NWB)           // 6145

typedef unsigned short u16;
typedef __bf16 bf16x8 __attribute__((ext_vector_type(8)));
typedef float f32x4 __attribute__((ext_vector_type(4)));
typedef unsigned short ushort8 __attribute__((ext_vector_type(8)));

// ---------- helpers ----------
__device__ __forceinline__ u16 f2bf(float f) {
  unsigned int u = __float_as_uint(f);
  unsigned int r = u + 0x7fffu + ((u >> 16) & 1u);   // RNE
  return (u16)(r >> 16);
}

__device__ __forceinline__ void gld16(const void* g, void* l) {
  __builtin_amdgcn_global_load_lds(
      (const __attribute__((address_space(1))) void*)g,
      (__attribute__((address_space(3))) void*)l, 16, 0, 0);
}

// wait for own vmcnt<=N (lgkm/exp untouched), then workgroup barrier.
// imm: vmcnt[3:0] | expcnt[6:4] | lgkmcnt[11:8]
#define PIPE_BARRIER_VM2() do {                    \
    asm volatile("" ::: "memory");                 \
    __builtin_amdgcn_s_waitcnt(0x0F72);            \
    __builtin_amdgcn_s_barrier();                  \
    asm volatile("" ::: "memory");                 \
  } while (0)
#define PIPE_BARRIER_VM0() do {                    \
    asm volatile("" ::: "memory");                 \
    __builtin_amdgcn_s_waitcnt(0x0F70);            \
    __builtin_amdgcn_s_barrier();                  \
    asm volatile("" ::: "memory");                 \
  } while (0)

// ---------- D1: routing (block 0) + x->bf16 natural (1..4096) + W1^T (4097..6144) ----
__global__ __launch_bounds__(256) void prep_k(
    const float* __restrict__ x, const int* __restrict__ sidx,
    const float* __restrict__ W1,
    u16* __restrict__ xb, u16* __restrict__ w1t,
    int* __restrict__ off, int* __restrict__ perm) {
  int bid = blockIdx.x;
  int t = threadIdx.x;

  if (bid == 0) {
    // ---- routing (single block, 256 threads, 4 waves) ----
    __shared__ int hist[4][En];
    __shared__ int base[4][En];
    __shared__ int eoff[En + 1];
    int wv = t >> 6;
    if (t < 4 * En) ((int*)hist)[t] = 0;
#pragma unroll
    for (int i = 0; i < PERM_N / 256; i++) perm[t + i * 256] = -1;  // pad fill
    __syncthreads();
    int e32[32], r32[32];
#pragma unroll
    for (int i = 0; i < 32; i++) {
      int e = sidx[t + i * 256];
      e32[i] = e;
      r32[i] = atomicAdd(&hist[wv][e], 1);
    }
    __syncthreads();
    if (t < En) {
      int s = 0;
      for (int w = 0; w < 4; w++) { base[w][t] = s; s += hist[w][t]; }
      hist[0][t] = s;
    }
    __syncthreads();
    if (t == 0) {
      int o = 0;
      for (int e = 0; e < En; e++) {
        eoff[e] = o; off[e] = o;
        o += (hist[0][e] + MT - 1) & ~(MT - 1);
      }
      eoff[En] = o; off[En] = o;
    }
    __syncthreads();
#pragma unroll
    for (int i = 0; i < 32; i++) {
      int e = e32[i];
      perm[eoff[e] + base[wv][e] + r32[i]] = t + i * 256;
    }
  } else if (bid < WB0) {
    // ---- x fp32 -> bf16, natural order (no perm dependency) ----
    size_t idx = ((size_t)(bid - XB0) * 256 + t) * 8;
    const float* src = x + idx;
    float4 a = *(const float4*)src;
    float4 b = *(const float4*)(src + 4);
    ushort8 o;
    o[0] = f2bf(a.x); o[1] = f2bf(a.y); o[2] = f2bf(a.z); o[3] = f2bf(a.w);
    o[4] = f2bf(b.x); o[5] = f2bf(b.y); o[6] = f2bf(b.z); o[7] = f2bf(b.w);
    *(ushort8*)(xb + idx) = o;
  } else {
    // ---- W1 [E][D][H] fp32 -> W1t [E][H][D] bf16, 64x64 LDS transpose ----
    __shared__ float tile[64][65];
    int wb = bid - WB0;
    int e = wb >> 8;
    int k0 = ((wb >> 4) & 15) * 64;   // D
    int n0 = (wb & 15) * 64;          // H
    int c4 = (t & 15) * 4;
    int r0 = t >> 4;                  // 0..15
    const float* src = W1 + ((size_t)e << 20) + (size_t)k0 * Hn + n0;
#pragma unroll
    for (int i = 0; i < 4; i++) {
      int r = r0 + i * 16;
      float4 v = *(const float4*)(src + (size_t)r * Hn + c4);
      tile[r][c4 + 0] = v.x; tile[r][c4 + 1] = v.y;
      tile[r][c4 + 2] = v.z; tile[r][c4 + 3] = v.w;
    }
    __syncthreads();
    u16* dst = w1t + ((size_t)e << 20) + (size_t)n0 * Dn + k0;
#pragma unroll
    for (int i = 0; i < 4; i++) {
      int h = r0 + i * 16;
      ushort4 o;
      o.x = f2bf(tile[c4 + 0][h]);
      o.y = f2bf(tile[c4 + 1][h]);
      o.z = f2bf(tile[c4 + 2][h]);
      o.w = f2bf(tile[c4 + 3][h]);
      *(ushort4*)(dst + (size_t)h * Dn + c4) = o;
    }
  }
}

// ---------- D2: grouped GEMM, 128x128 tile, 512 threads (8 waves),
// ---------- 3-stage vmcnt(2) pipeline, in-staging A-gather, partials epilogue ----
__global__ __launch_bounds__(512) void gemm_k(
    const u16* __restrict__ xb, const u16* __restrict__ w1t,
    const float* __restrict__ b1, const float* __restrict__ w2,
    const int* __restrict__ off, const int* __restrict__ perm,
    float* __restrict__ partials) {
  __shared__ u16 As[3][4096];   // 3 stages x 128 rows x 32 k (8 KB each)
  __shared__ u16 Bs[3][4096];

  int n0 = blockIdx.x * 128;            // x = n-tile (8): pins n-slice to one XCD
  int row0 = blockIdx.y * MT;
  if (row0 >= off[En]) return;          // dead (all-pad) tile
  int e = 0;
  while (row0 >= off[e + 1]) e++;

  int tid = threadIdx.x;
  int lane = tid & 63, w = tid >> 6;    // 8 waves
  int wm = w >> 1, wn = w & 1;          // wave tile: rows 32*wm, cols 64*wn

  // staging: HW puts lane L at LDS base + L*16B -> (row L>>2, slot L&3).
  // source chunk q = slot ^ swz(row) implements the xor swizzle.
  // wave w stages A rows [16w,16w+16) and B rows [16w,16w+16): 1 load each.
  int srow = lane >> 2;
  int slot = lane & 3;
  int scol = (slot ^ ((srow >> 1) & 3)) * 8;
  int rl = 16 * w + srow;
  int tokA = perm[row0 + rl];
  if (tokA < 0) tokA = 0;               // pad row: any valid row (result discarded)
  const u16* aG = xb + ((size_t)tokA << 10) + scol;
  const u16* bG = w1t + ((size_t)e << 20) + (size_t)(n0 + rl) * Dn + scol;
  int lOff = (16 * w) * 32;             // wave-uniform LDS base (elements)

  f32x4 acc[2][4];
#pragma unroll
  for (int i = 0; i < 2; i++)
#pragma unroll
    for (int j = 0; j < 4; j++)
      acc[i][j] = (f32x4){0.f, 0.f, 0.f, 0.f};

  int fr = lane & 15;
  int qf = lane >> 4;
  int qs = (qf ^ ((fr >> 1) & 3)) * 8;
  int offA[2], offB[4];
#pragma unroll
  for (int i = 0; i < 2; i++)
    offA[i] = (wm * 32 + i * 16 + fr) * 32 + qs;
#pragma unroll
  for (int j = 0; j < 4; j++)
    offB[j] = (wn * 64 + j * 16 + fr) * 32 + qs;

  // prologue: stages 0,1 in flight (2 loads/thread each)
#pragma unroll
  for (int it = 0; it < 2; it++) {
    int ko = it * 32;
    gld16(aG + ko, (u16*)As[it] + lOff);
    gld16(bG + ko, (u16*)Bs[it] + lOff);
  }

#pragma unroll
  for (int i = 0; i < 31; i++) {
    PIPE_BARRIER_VM2();                 // stage-i loads done; stage-(i+1) in flight
    if (i + 2 < 32) {
      int s = (i + 2) % 3;
      int ko = (i + 2) * 32;
      gld16(aG + ko, (u16*)As[s] + lOff);
      gld16(bG + ko, (u16*)Bs[s] + lOff);
    }
    const u16* Ab = (const u16*)As[i % 3];
    const u16* Bb = (const u16*)Bs[i % 3];
    bf16x8 af[2], bfr[4];
#pragma unroll
    for (int ii = 0; ii < 2; ii++) af[ii] = *(const bf16x8*)(Ab + offA[ii]);
#pragma unroll
    for (int jj = 0; jj < 4; jj++) bfr[jj] = *(const bf16x8*)(Bb + offB[jj]);
#pragma unroll
    for (int ii = 0; ii < 2; ii++)
#pragma unroll
      for (int jj = 0; jj < 4; jj++)
        acc[ii][jj] = __builtin_amdgcn_mfma_f32_16x16x32_bf16(af[ii], bfr[jj], acc[ii][jj], 0, 0, 0);
  }
  {                                     // peeled last iteration (full drain)
    PIPE_BARRIER_VM0();
    const u16* Ab = (const u16*)As[31 % 3];
    const u16* Bb = (const u16*)Bs[31 % 3];
    bf16x8 af[2], bfr[4];
#pragma unroll
    for (int ii = 0; ii < 2; ii++) af[ii] = *(const bf16x8*)(Ab + offA[ii]);
#pragma unroll
    for (int jj = 0; jj < 4; jj++) bfr[jj] = *(const bf16x8*)(Bb + offB[jj]);
#pragma unroll
    for (int ii = 0; ii < 2; ii++)
#pragma unroll
      for (int jj = 0; jj < 4; jj++)
        acc[ii][jj] = __builtin_amdgcn_mfma_f32_16x16x32_bf16(af[ii], bfr[jj], acc[ii][jj], 0, 0, 0);
  }

  // epilogue: h = relu(acc + b1); partial = h . W2[e][col][0..3]; float4 per row/chunk
  float4 w2v[4]; float b1v[4];
#pragma unroll
  for (int j = 0; j < 4; j++) {
    int col = n0 + wn * 64 + j * 16 + fr;
    w2v[j] = *(const float4*)(w2 + ((size_t)e * Hn + col) * 4);
    b1v[j] = b1[(size_t)e * Hn + col];
  }
  int chunk = blockIdx.x * 2 + wn;      // 64-col chunk 0..15
#pragma unroll
  for (int i = 0; i < 2; i++) {
    int rbase = wm * 32 + i * 16 + qf * 4;
#pragma unroll
    for (int r = 0; r < 4; r++) {
      float s0 = 0.f, s1 = 0.f, s2 = 0.f, s3 = 0.f;
#pragma unroll
      for (int j = 0; j < 4; j++) {
        float h = acc[i][j][r] + b1v[j];
        h = fmaxf(h, 0.f);
        s0 = fmaf(h, w2v[j].x, s0);
        s1 = fmaf(h, w2v[j].y, s1);
        s2 = fmaf(h, w2v[j].z, s2);
        s3 = fmaf(h, w2v[j].w, s3);
      }
#pragma unroll
      for (int m = 1; m < 16; m <<= 1) {
        s0 += __shfl_xor(s0, m);
        s1 += __shfl_xor(s1, m);
        s2 += __shfl_xor(s2, m);
        s3 += __shfl_xor(s3, m);
      }
      if (fr == 0) {
        int row = row0 + rbase + r;
        *(float4*)(partials + ((size_t)row * NB + chunk) * 4) =
            make_float4(s0, s1, s2, s3);
      }
    }
  }
}

// ---------- D3: reduce partials + ordinal probs ----------
__global__ void probs_k(const float* __restrict__ partials,
                        const int* __restrict__ perm, const int* __restrict__ off,
                        const int* __restrict__ sidx, const float* __restrict__ b2,
                        float* __restrict__ out) {
  int p = blockIdx.x * blockDim.x + threadIdx.x;
  if (p >= off[En]) return;
  int tok = perm[p];
  if (tok < 0) return;
  int e = sidx[tok];
  float s0 = 0.f, s1 = 0.f, s2 = 0.f, s3 = 0.f;
#pragma unroll
  for (int nb = 0; nb < NB; nb++) {
    float4 v = *(const float4*)(partials + ((size_t)p * NB + nb) * 4);
    s0 += v.x; s1 += v.y; s2 += v.z; s3 += v.w;
  }
  float l0 = s0 + b2[e * 4 + 0];
  float l1 = s1 + b2[e * 4 + 1];
  float l2 = s2 + b2[e * 4 + 2];
  float l3 = s3 + b2[e * 4 + 3];
  out[tok * 4 + 0] = l0; out[tok * 4 + 1] = l1;
  out[tok * 4 + 2] = l2; out[tok * 4 + 3] = l3;
  float q0 = 1.f / (1.f + expf(-l0));
  float q1 = 1.f / (1.f + expf(-l1));
  float q2 = 1.f / (1.f + expf(-l2));
  float q3 = 1.f / (1.f + expf(-l3));
  const float eps = 1e-8f;
  float p0 = fmaxf(1.f - q0, eps);
  float p1 = fmaxf(q0 - q1, eps);
  float p2 = fmaxf(q1 - q2, eps);
  float p3 = fmaxf(q2 - q3, eps);
  float p4 = fmaxf(q3, eps);
  float s = p0 + p1 + p2 + p3 + p4;
  float inv = 1.f / fmaxf(s, eps);
  float* pr = out + (size_t)Bn * 4 + (size_t)tok * 5;
  pr[0] = p0 * inv; pr[1] = p1 * inv; pr[2] = p2 * inv;
  pr[3] = p3 * inv; pr[4] = p4 * inv;
}

// ---------- launch ----------
extern "C" void kernel_launch(void* const* d_in, const int* in_sizes, int n_in,
                              void* d_out, int out_size, void* d_ws, size_t ws_size,
                              hipStream_t stream) {
  const float* x  = (const float*)d_in[0];
  const int* sidx = (const int*)d_in[1];
  const float* W1 = (const float*)d_in[2];
  const float* b1 = (const float*)d_in[3];
  const float* W2 = (const float*)d_in[4];
  const float* b2 = (const float*)d_in[5];
  float* out = (float*)d_out;

  uint8_t* w = (uint8_t*)d_ws;
  int* off  = (int*)(w + 64);     // 9 ints
  int* perm = (int*)(w + 512);    // 9216 ints
  u16* xb      = (u16*)(w + 40960);                    // 16,777,216 B
  u16* w1t     = (u16*)(w + 40960 + 16777216);         // 16,777,216 B
  float* parts = (float*)(w + 40960 + 2 * 16777216);   // 2,359,296 B

  prep_k<<<TOTB, 256, 0, stream>>>(x, sidx, W1, xb, w1t, off, perm);
  gemm_k<<<dim3(8, MTILES), 512, 0, stream>>>(xb, w1t, b1, W2, off, perm, parts);
  probs_k<<<(PERM_N + 255) / 256, 256, 0, stream>>>(parts, perm, off, sidx, b2, out);
}